// Round 7
// baseline (719.898 us; speedup 1.0000x reference)
//
#include <hip/hip_runtime.h>
#include <hip/hip_fp16.h>
#include <math.h>

#define HDIM 128
#define BKT_SHIFT 7          // 128 nodes per bucket
#define NBMAX 512            // max buckets (N <= 65536)
#define CHUNK 4096           // edges per bucket_scatter block

typedef __attribute__((ext_vector_type(8))) short bf16x8;
typedef __attribute__((ext_vector_type(4))) float f32x4;

union U4 { unsigned int u[4]; bf16x8 v; };

__device__ __forceinline__ unsigned int cvt_pk_bf16(float a, float b) {
    unsigned int r;
    asm("v_cvt_pk_bf16_f32 %0, %1, %2" : "=v"(r) : "v"(a), "v"(b));
    return r;
}

// split 8 fp32 -> hi bf16x8 + lo bf16x8 (x ~= hi + lo, error ~2^-17 |x|)
__device__ __forceinline__ void split8(const float* v, bf16x8& ah, bf16x8& al) {
    U4 H, L;
    #pragma unroll
    for (int p = 0; p < 4; p++) {
        unsigned int h = cvt_pk_bf16(v[2 * p], v[2 * p + 1]);
        H.u[p] = h;
        float h0 = __uint_as_float(h << 16);
        float h1 = __uint_as_float(h & 0xFFFF0000u);
        L.u[p] = cvt_pk_bf16(v[2 * p] - h0, v[2 * p + 1] - h1);
    }
    ah = H.v; al = L.v;
}

// ================= CSR build via two-level binning =================
// phase 1: per-bucket counts
__global__ void bucket_hist(const int* __restrict__ dst, int* __restrict__ bcount, int E) {
    int i = blockIdx.x * blockDim.x + threadIdx.x;
    int stride = gridDim.x * blockDim.x;
    for (; i < E; i += stride) atomicAdd(&bcount[dst[i] >> BKT_SHIFT], 1);
}

// phase 2: exclusive scan of 512 bucket counts -> bases + cursors (1 block)
__global__ __launch_bounds__(256) void bucket_scan(const int* __restrict__ bcount,
                                                   int* __restrict__ bases,
                                                   int* __restrict__ cursor, int E) {
    int t = threadIdx.x;
    int v0 = bcount[2 * t], v1 = bcount[2 * t + 1];
    int s = v0 + v1;
    __shared__ int ss[256];
    ss[t] = s; __syncthreads();
    #pragma unroll
    for (int off = 1; off < 256; off <<= 1) {
        int u = (t >= off) ? ss[t - off] : 0;
        __syncthreads();
        ss[t] += u;
        __syncthreads();
    }
    int ex = ss[t] - s;
    bases[2 * t] = ex;          cursor[2 * t] = ex;
    bases[2 * t + 1] = ex + v0; cursor[2 * t + 1] = ex + v0;
    if (t == 255) bases[NBMAX] = E;
}

// phase 3: LDS-binned scatter of packed edges into bucket-contiguous ebuf
// pack: bits 24..30 = dst&127, bits 0..23 = src  (requires N < 2^24)
__global__ __launch_bounds__(256) void bucket_scatter(const int* __restrict__ src,
                                                      const int* __restrict__ dst,
                                                      int* __restrict__ cursor,
                                                      unsigned* __restrict__ ebuf, int E) {
    __shared__ unsigned sbuf[CHUNK];
    __shared__ int hist[NBMAX], hbase[NBMAX], gbase[NBMAX], cnt2[NBMAX];
    __shared__ int ss[256];
    int t = threadIdx.x;
    int start = blockIdx.x * CHUNK;
    int n = min(CHUNK, E - start);

    for (int b = t; b < NBMAX; b += 256) { hist[b] = 0; cnt2[b] = 0; }
    __syncthreads();
    for (int i = t; i < n; i += 256) atomicAdd(&hist[dst[start + i] >> BKT_SHIFT], 1);
    __syncthreads();

    // scan 512 bins with 256 threads (pairwise)
    int v0 = hist[2 * t], v1 = hist[2 * t + 1];
    int s = v0 + v1;
    ss[t] = s; __syncthreads();
    #pragma unroll
    for (int off = 1; off < 256; off <<= 1) {
        int u = (t >= off) ? ss[t - off] : 0;
        __syncthreads();
        ss[t] += u;
        __syncthreads();
    }
    int ex = ss[t] - s;
    hbase[2 * t] = ex;
    hbase[2 * t + 1] = ex + v0;
    if (v0 > 0) gbase[2 * t] = atomicAdd(&cursor[2 * t], v0);
    if (v1 > 0) gbase[2 * t + 1] = atomicAdd(&cursor[2 * t + 1], v1);
    __syncthreads();

    // scatter into LDS, bucket-ordered
    for (int i = t; i < n; i += 256) {
        int d = dst[start + i];
        int bkt = d >> BKT_SHIFT;
        unsigned p = ((unsigned)(d & 127) << 24) | (unsigned)src[start + i];
        int pos = atomicAdd(&cnt2[bkt], 1);
        sbuf[hbase[bkt] + pos] = p;
    }
    __syncthreads();

    // flush contiguous per-bucket runs
    for (int b = t; b < NBMAX; b += 256) {
        int c = hist[b], hb = hbase[b], gb = gbase[b];
        for (int j = 0; j < c; j++) ebuf[gb + j] = sbuf[hb + j];
    }
}

// phase 4: per-bucket exact CSR + degrees + offs + dinv (fully coalesced)
__global__ __launch_bounds__(256) void bucket_finalize(const unsigned* __restrict__ ebuf,
                                                       const int* __restrict__ bases,
                                                       int* __restrict__ csr,
                                                       int* __restrict__ offs,
                                                       float* __restrict__ dinv,
                                                       int N, int E) {
    int b = blockIdx.x;
    int beg = bases[b], end = bases[b + 1];
    __shared__ int hist[128], pre[128], cnt2[128];
    int t = threadIdx.x;
    if (t < 128) { hist[t] = 0; cnt2[t] = 0; }
    __syncthreads();
    for (int i = beg + t; i < end; i += 256)
        atomicAdd(&hist[(ebuf[i] >> 24) & 127], 1);
    __syncthreads();
    if (t < 128) pre[t] = hist[t];
    __syncthreads();
    #pragma unroll
    for (int off = 1; off < 128; off <<= 1) {
        int v = (t < 128 && t >= off) ? pre[t - off] : 0;
        __syncthreads();
        if (t < 128) pre[t] += v;
        __syncthreads();
    }
    if (t < 128) {
        int node = b * 128 + t;
        if (node < N) {
            int ex = pre[t] - hist[t];
            offs[node] = beg + ex;
            dinv[node] = rsqrtf((float)hist[t] + 1.0f);
        }
    }
    if (b == 0 && t == 0) offs[N] = E;
    __syncthreads();
    for (int i = beg + t; i < end; i += 256) {
        unsigned p = ebuf[i];
        int dl = (p >> 24) & 127;
        int pos = atomicAdd(&cnt2[dl], 1);
        csr[beg + (pre[dl] - hist[dl]) + pos] = (int)(p & 0xFFFFFFu);
    }
}

// ---------------- weight split: W[k][n] fp32 -> Wh/Wl[n][k] bf16 (RNE) ----------------
__global__ void wsplit_kernel(const float* __restrict__ Wsrc, short* __restrict__ Whi,
                              short* __restrict__ Wlo) {
    int i = blockIdx.x * 256 + threadIdx.x;   // i = n*128 + k
    if (i >= 128 * 128) return;
    int n = i >> 7, k = i & 127;
    float v = Wsrc[k * 128 + n];
    unsigned int u = __float_as_uint(v);
    unsigned int hi = (u + 0x7FFFu + ((u >> 16) & 1)) & 0xFFFF0000u;
    float hf = __uint_as_float(hi);
    float lo = v - hf;
    unsigned int ul = __float_as_uint(lo);
    unsigned int lo16 = (ul + 0x7FFFu + ((ul >> 16) & 1)) >> 16;
    Whi[i] = (short)(hi >> 16);
    Wlo[i] = (short)lo16;
}

// ---------------- MFMA GEMM: C[N x 128] = affine(A)[N x 128] @ W[128 x 128] ----------------
template <bool OUT_F16>
__global__ __launch_bounds__(256) void gemm_mfma(const float* __restrict__ A,
                                                 const short* __restrict__ Wh,
                                                 const short* __restrict__ Wl,
                                                 const float* __restrict__ aff_s,
                                                 const float* __restrict__ aff_t,
                                                 const float* __restrict__ bias,
                                                 const float* __restrict__ rowscale,
                                                 void* __restrict__ outp, int N) {
    int w = threadIdx.x >> 6;
    int lane = threadIdx.x & 63;
    int l15 = lane & 15, lg = lane >> 4;
    int r0 = blockIdx.x * 128 + (w >> 1) * 64;
    int c0 = (w & 1) * 64;

    f32x4 acc[4][4];
    #pragma unroll
    for (int tc = 0; tc < 4; tc++) {
        float bz = bias ? bias[c0 + tc * 16 + l15] : 0.0f;
        #pragma unroll
        for (int tr = 0; tr < 4; tr++) {
            acc[tr][tc][0] = bz; acc[tr][tc][1] = bz;
            acc[tr][tc][2] = bz; acc[tr][tc][3] = bz;
        }
    }

    #pragma unroll
    for (int kt = 0; kt < 4; kt++) {
        int kk = kt * 32 + lg * 8;

        bf16x8 bh[4], bl[4];
        #pragma unroll
        for (int tc = 0; tc < 4; tc++) {
            int n = c0 + tc * 16 + l15;
            bh[tc] = *(const bf16x8*)(Wh + n * 128 + kk);
            bl[tc] = *(const bf16x8*)(Wl + n * 128 + kk);
        }

        float sv[8], tv[8];
        if (aff_s) {
            *(float4*)&sv[0] = *(const float4*)(aff_s + kk);
            *(float4*)&sv[4] = *(const float4*)(aff_s + kk + 4);
            *(float4*)&tv[0] = *(const float4*)(aff_t + kk);
            *(float4*)&tv[4] = *(const float4*)(aff_t + kk + 4);
        }

        bf16x8 ah[4], al[4];
        #pragma unroll
        for (int tr = 0; tr < 4; tr++) {
            int row = min(r0 + tr * 16 + l15, N - 1);
            const float* ap = A + (size_t)row * 128 + kk;
            float v[8];
            *(float4*)&v[0] = *(const float4*)ap;
            *(float4*)&v[4] = *(const float4*)(ap + 4);
            if (aff_s) {
                #pragma unroll
                for (int j = 0; j < 8; j++) v[j] = fmaf(v[j], sv[j], tv[j]);
            }
            split8(v, ah[tr], al[tr]);
        }

        #pragma unroll
        for (int tr = 0; tr < 4; tr++) {
            #pragma unroll
            for (int tc = 0; tc < 4; tc++) {
                acc[tr][tc] = __builtin_amdgcn_mfma_f32_16x16x32_bf16(ah[tr], bh[tc], acc[tr][tc], 0, 0, 0);
                acc[tr][tc] = __builtin_amdgcn_mfma_f32_16x16x32_bf16(ah[tr], bl[tc], acc[tr][tc], 0, 0, 0);
                acc[tr][tc] = __builtin_amdgcn_mfma_f32_16x16x32_bf16(al[tr], bh[tc], acc[tr][tc], 0, 0, 0);
            }
        }
    }

    #pragma unroll
    for (int tr = 0; tr < 4; tr++) {
        #pragma unroll
        for (int r = 0; r < 4; r++) {
            int row = r0 + tr * 16 + lg * 4 + r;
            if (row < N) {
                float sc = rowscale ? rowscale[row] : 1.0f;
                #pragma unroll
                for (int tc = 0; tc < 4; tc++) {
                    int col = c0 + tc * 16 + l15;
                    float val = acc[tr][tc][r] * sc;
                    if (OUT_F16) {
                        ((__half*)outp)[(size_t)row * 128 + col] = __float2half(val);
                    } else {
                        ((float*)outp)[(size_t)row * 128 + col] = val;
                    }
                }
            }
        }
    }
}

// ---------------- gather (fp16 in, fp32 out) ----------------
__global__ __launch_bounds__(256) void gather_kernel(const __half* __restrict__ hws,
                                                     const int* __restrict__ csr_src,
                                                     const int* __restrict__ offs,
                                                     const float* __restrict__ dinv,
                                                     const float* __restrict__ bias,
                                                     float* __restrict__ out,
                                                     int N, int relu) {
    int lane = threadIdx.x & 63;
    int node = blockIdx.x * 4 + (threadIdx.x >> 6);
    if (node >= N) return;
    int lo = offs[node], hi = offs[node + 1];

    float2 acc = make_float2(0.f, 0.f);
    int j = lo;
    for (; j + 3 < hi; j += 4) {
        int s0 = csr_src[j], s1 = csr_src[j + 1], s2 = csr_src[j + 2], s3 = csr_src[j + 3];
        float2 v0 = __half22float2(((const __half2*)(hws + (size_t)s0 * HDIM))[lane]);
        float2 v1 = __half22float2(((const __half2*)(hws + (size_t)s1 * HDIM))[lane]);
        float2 v2 = __half22float2(((const __half2*)(hws + (size_t)s2 * HDIM))[lane]);
        float2 v3 = __half22float2(((const __half2*)(hws + (size_t)s3 * HDIM))[lane]);
        acc.x += v0.x + v1.x + v2.x + v3.x;
        acc.y += v0.y + v1.y + v2.y + v3.y;
    }
    for (; j < hi; j++) {
        int s = csr_src[j];
        float2 v = __half22float2(((const __half2*)(hws + (size_t)s * HDIM))[lane]);
        acc.x += v.x; acc.y += v.y;
    }
    float2 vs = __half22float2(((const __half2*)(hws + (size_t)node * HDIM))[lane]);
    float di = dinv[node];
    float2 b = ((const float2*)bias)[lane];
    float ox = di * (acc.x + vs.x) + b.x;
    float oy = di * (acc.y + vs.y) + b.y;
    if (relu) { ox = fmaxf(ox, 0.f); oy = fmaxf(oy, 0.f); }
    ((float2*)(out + (size_t)node * HDIM))[lane] = make_float2(ox, oy);
}

// ---------------- batchnorm stats ----------------
__global__ __launch_bounds__(256) void bn_stats_kernel(const float* __restrict__ h,
                                                       float* __restrict__ stats, int N) {
    int f = threadIdx.x & 127;
    int half_ = threadIdx.x >> 7;
    float s = 0.f, s2 = 0.f;
    for (int n = blockIdx.x * 2 + half_; n < N; n += gridDim.x * 2) {
        float v = h[(size_t)n * HDIM + f];
        s += v;
        s2 += v * v;
    }
    __shared__ float ls[256], ls2[256];
    ls[threadIdx.x] = s;
    ls2[threadIdx.x] = s2;
    __syncthreads();
    if (half_ == 0) {
        s = ls[f] + ls[f + 128];
        s2 = ls2[f] + ls2[f + 128];
        atomicAdd(&stats[f], s);
        atomicAdd(&stats[128 + f], s2);
    }
}

__global__ void bn_finalize(const float* __restrict__ stats, const float* __restrict__ gamma,
                            const float* __restrict__ beta, float* __restrict__ aff_s,
                            float* __restrict__ aff_t, int N) {
    int f = threadIdx.x;  // 128
    float inv = 1.0f / (float)N;
    float m = stats[f] * inv;
    float var = stats[128 + f] * inv - m * m;
    float s = gamma[f] * rsqrtf(var + 1e-5f);
    aff_s[f] = s;
    aff_t[f] = beta[f] - m * s;
}

// ---------------- pool ----------------
__device__ __forceinline__ int lower_bound_i(const int* __restrict__ arr, int n, int val) {
    int lo = 0, hi = n;
    while (lo < hi) {
        int mid = (lo + hi) >> 1;
        if (arr[mid] < val) lo = mid + 1; else hi = mid;
    }
    return lo;
}

__global__ void pool_kernel(const float* __restrict__ h, const int* __restrict__ batch,
                            float* __restrict__ out, int N, int G) {
    int g = blockIdx.x;
    int lo = lower_bound_i(batch, N, g);
    int hi = lower_bound_i(batch, N, g + 1);
    int f = threadIdx.x;
    float s = 0.f;
    for (int n = lo; n < hi; n++) s += h[(size_t)n * HDIM + f];
    float cnt = (float)(hi - lo);
    out[(size_t)g * HDIM + f] = s / fmaxf(cnt, 1.0f);
}

// ---------------- launch ----------------
extern "C" void kernel_launch(void* const* d_in, const int* in_sizes, int n_in,
                              void* d_out, int out_size, void* d_ws, size_t ws_size,
                              hipStream_t stream) {
    const float* x      = (const float*)d_in[0];
    const int*   ei     = (const int*)d_in[1];
    const int*   batch  = (const int*)d_in[2];
    const float* W_emb  = (const float*)d_in[3];
    const float* b_emb  = (const float*)d_in[4];
    const float* W_conv = (const float*)d_in[5];
    const float* b_conv = (const float*)d_in[6];
    const float* gamma  = (const float*)d_in[7];
    const float* beta   = (const float*)d_in[8];

    const int E = in_sizes[1] / 2;
    const int N = in_sizes[2];
    const int G = out_size / HDIM;
    const int DEPTH = 4;

    const int* srcp = ei;
    const int* dstp = ei + E;
    float* out = (float*)d_out;

    size_t NH = (size_t)N * HDIM;
    size_t npad = ((size_t)N + 63) & ~(size_t)63;
    size_t epad = ((size_t)E + 63) & ~(size_t)63;
    int nb = (N + 127) / 128;  // buckets (<= NBMAX)

    float* ws = (float*)d_ws;
    float* dinv    = ws;                           // npad
    int*   offs    = (int*)(dinv + npad);          // npad + 64
    int*   bases   = offs + npad + 64;             // NBMAX+1 (pad 1024)
    int*   cursor  = bases + 1024;                 // NBMAX
    int*   bcount  = cursor + NBMAX;               // NBMAX
    int*   csr     = bcount + NBMAX;               // epad
    unsigned* ebuf = (unsigned*)(csr + epad);      // epad
    float* stats   = (float*)(ebuf + epad);        // 256
    float* aff_s   = stats + 256;                  // 128
    float* aff_t   = aff_s + 128;                  // 128
    short* wt      = (short*)(aff_t + 128);        // 5 * 2 * 16384 shorts
    float* hbuf    = (float*)(wt + 5 * 2 * 16384); // NH floats
    __half* hws16  = (__half*)(hbuf + NH);         // NH halves

    // ---- weight split (5 matrices: emb + 4 conv) ----
    wsplit_kernel<<<64, 256, 0, stream>>>(W_emb, wt, wt + 16384);
    for (int l = 0; l < DEPTH; l++) {
        short* whi = wt + (size_t)(l + 1) * 32768;
        wsplit_kernel<<<64, 256, 0, stream>>>(W_conv + (size_t)l * 16384, whi, whi + 16384);
    }

    // ---- CSR build (two-level binning) ----
    hipMemsetAsync(bcount, 0, NBMAX * sizeof(int), stream);
    bucket_hist<<<512, 256, 0, stream>>>(dstp, bcount, E);
    bucket_scan<<<1, 256, 0, stream>>>(bcount, bases, cursor, E);
    bucket_scatter<<<(E + CHUNK - 1) / CHUNK, 256, 0, stream>>>(srcp, dstp, cursor, ebuf, E);
    bucket_finalize<<<nb, 256, 0, stream>>>(ebuf, bases, csr, offs, dinv, N, E);

    int gemm_blocks = (N + 127) / 128;

    // ---- embedding: hbuf = x @ W_emb + b_emb (fp32 out) ----
    gemm_mfma<false><<<gemm_blocks, 256, 0, stream>>>(x, wt, wt + 16384, nullptr, nullptr,
                                                      b_emb, nullptr, hbuf, N);

    int gather_blocks = (N + 3) / 4;

    for (int l = 0; l < DEPTH; l++) {
        short* whi = wt + (size_t)(l + 1) * 32768;
        gemm_mfma<true><<<gemm_blocks, 256, 0, stream>>>(hbuf, whi, whi + 16384,
                                                         (l > 0) ? aff_s : nullptr,
                                                         (l > 0) ? aff_t : nullptr,
                                                         nullptr, dinv, hws16, N);
        gather_kernel<<<gather_blocks, 256, 0, stream>>>(hws16, csr, offs, dinv,
                                                         b_conv + (size_t)l * HDIM, hbuf,
                                                         N, (l < DEPTH - 1) ? 1 : 0);
        if (l < DEPTH - 1) {
            hipMemsetAsync(stats, 0, 256 * sizeof(float), stream);
            bn_stats_kernel<<<512, 256, 0, stream>>>(hbuf, stats, N);
            bn_finalize<<<1, 128, 0, stream>>>(stats, gamma + (size_t)l * HDIM,
                                               beta + (size_t)l * HDIM, aff_s, aff_t, N);
        }
    }

    pool_kernel<<<G, HDIM, 0, stream>>>(hbuf, batch, out, N, G);
}

// Round 8
// 448.786 us; speedup vs baseline: 1.6041x; 1.6041x over previous
//
#include <hip/hip_runtime.h>
#include <hip/hip_fp16.h>
#include <math.h>

#define HDIM 128
#define BKT_SHIFT 7          // 128 nodes per bucket
#define NBMAX 512            // max buckets (N <= 65536)
#define CHUNK 4096           // edges per bucket_scatter block

typedef __attribute__((ext_vector_type(8))) short bf16x8;
typedef __attribute__((ext_vector_type(4))) float f32x4;

union U4 { unsigned int u[4]; bf16x8 v; };

__device__ __forceinline__ unsigned int cvt_pk_bf16(float a, float b) {
    unsigned int r;
    asm("v_cvt_pk_bf16_f32 %0, %1, %2" : "=v"(r) : "v"(a), "v"(b));
    return r;
}

// split 8 fp32 -> hi bf16x8 + lo bf16x8 (x ~= hi + lo, error ~2^-17 |x|)
__device__ __forceinline__ void split8(const float* v, bf16x8& ah, bf16x8& al) {
    U4 H, L;
    #pragma unroll
    for (int p = 0; p < 4; p++) {
        unsigned int h = cvt_pk_bf16(v[2 * p], v[2 * p + 1]);
        H.u[p] = h;
        float h0 = __uint_as_float(h << 16);
        float h1 = __uint_as_float(h & 0xFFFF0000u);
        L.u[p] = cvt_pk_bf16(v[2 * p] - h0, v[2 * p + 1] - h1);
    }
    ah = H.v; al = L.v;
}

// ================= CSR build via two-level binning =================
// phase 1: per-bucket counts — LDS-privatized (fix for global-atomic contention)
__global__ __launch_bounds__(256) void bucket_hist(const int* __restrict__ dst,
                                                   int* __restrict__ bcount, int E) {
    __shared__ int h[NBMAX];
    int t = threadIdx.x;
    for (int b = t; b < NBMAX; b += 256) h[b] = 0;
    __syncthreads();
    int i = blockIdx.x * blockDim.x + t;
    int stride = gridDim.x * blockDim.x;
    for (; i < E; i += stride) atomicAdd(&h[dst[i] >> BKT_SHIFT], 1);
    __syncthreads();
    for (int b = t; b < NBMAX; b += 256) {
        int c = h[b];
        if (c) atomicAdd(&bcount[b], c);
    }
}

// phase 2: exclusive scan of 512 bucket counts -> bases + cursors (1 block)
__global__ __launch_bounds__(256) void bucket_scan(const int* __restrict__ bcount,
                                                   int* __restrict__ bases,
                                                   int* __restrict__ cursor, int E) {
    int t = threadIdx.x;
    int v0 = bcount[2 * t], v1 = bcount[2 * t + 1];
    int s = v0 + v1;
    __shared__ int ss[256];
    ss[t] = s; __syncthreads();
    #pragma unroll
    for (int off = 1; off < 256; off <<= 1) {
        int u = (t >= off) ? ss[t - off] : 0;
        __syncthreads();
        ss[t] += u;
        __syncthreads();
    }
    int ex = ss[t] - s;
    bases[2 * t] = ex;          cursor[2 * t] = ex;
    bases[2 * t + 1] = ex + v0; cursor[2 * t + 1] = ex + v0;
    if (t == 255) bases[NBMAX] = E;
}

// phase 3: LDS-binned scatter of packed edges into bucket-contiguous ebuf
// pack: bits 24..30 = dst&127, bits 0..23 = src  (requires N < 2^24)
__global__ __launch_bounds__(256) void bucket_scatter(const int* __restrict__ src,
                                                      const int* __restrict__ dst,
                                                      int* __restrict__ cursor,
                                                      unsigned* __restrict__ ebuf, int E) {
    __shared__ unsigned sbuf[CHUNK];
    __shared__ int hist[NBMAX], hbase[NBMAX], gbase[NBMAX], cnt2[NBMAX];
    __shared__ int ss[256];
    int t = threadIdx.x;
    int start = blockIdx.x * CHUNK;
    int n = min(CHUNK, E - start);

    for (int b = t; b < NBMAX; b += 256) { hist[b] = 0; cnt2[b] = 0; }
    __syncthreads();
    for (int i = t; i < n; i += 256) atomicAdd(&hist[dst[start + i] >> BKT_SHIFT], 1);
    __syncthreads();

    // scan 512 bins with 256 threads (pairwise)
    int v0 = hist[2 * t], v1 = hist[2 * t + 1];
    int s = v0 + v1;
    ss[t] = s; __syncthreads();
    #pragma unroll
    for (int off = 1; off < 256; off <<= 1) {
        int u = (t >= off) ? ss[t - off] : 0;
        __syncthreads();
        ss[t] += u;
        __syncthreads();
    }
    int ex = ss[t] - s;
    hbase[2 * t] = ex;
    hbase[2 * t + 1] = ex + v0;
    if (v0 > 0) gbase[2 * t] = atomicAdd(&cursor[2 * t], v0);
    if (v1 > 0) gbase[2 * t + 1] = atomicAdd(&cursor[2 * t + 1], v1);
    __syncthreads();

    // scatter into LDS, bucket-ordered
    for (int i = t; i < n; i += 256) {
        int d = dst[start + i];
        int bkt = d >> BKT_SHIFT;
        unsigned p = ((unsigned)(d & 127) << 24) | (unsigned)src[start + i];
        int pos = atomicAdd(&cnt2[bkt], 1);
        sbuf[hbase[bkt] + pos] = p;
    }
    __syncthreads();

    // flush contiguous per-bucket runs
    for (int b = t; b < NBMAX; b += 256) {
        int c = hist[b], hb = hbase[b], gb = gbase[b];
        for (int j = 0; j < c; j++) ebuf[gb + j] = sbuf[hb + j];
    }
}

// phase 4: per-bucket exact CSR + degrees + offs + dinv (fully coalesced)
__global__ __launch_bounds__(256) void bucket_finalize(const unsigned* __restrict__ ebuf,
                                                       const int* __restrict__ bases,
                                                       int* __restrict__ csr,
                                                       int* __restrict__ offs,
                                                       float* __restrict__ dinv,
                                                       int N, int E) {
    int b = blockIdx.x;
    int beg = bases[b], end = bases[b + 1];
    __shared__ int hist[128], pre[128], cnt2[128];
    int t = threadIdx.x;
    if (t < 128) { hist[t] = 0; cnt2[t] = 0; }
    __syncthreads();
    for (int i = beg + t; i < end; i += 256)
        atomicAdd(&hist[(ebuf[i] >> 24) & 127], 1);
    __syncthreads();
    if (t < 128) pre[t] = hist[t];
    __syncthreads();
    #pragma unroll
    for (int off = 1; off < 128; off <<= 1) {
        int v = (t < 128 && t >= off) ? pre[t - off] : 0;
        __syncthreads();
        if (t < 128) pre[t] += v;
        __syncthreads();
    }
    if (t < 128) {
        int node = b * 128 + t;
        if (node < N) {
            int ex = pre[t] - hist[t];
            offs[node] = beg + ex;
            dinv[node] = rsqrtf((float)hist[t] + 1.0f);
        }
    }
    if (b == 0 && t == 0) offs[N] = E;
    __syncthreads();
    for (int i = beg + t; i < end; i += 256) {
        unsigned p = ebuf[i];
        int dl = (p >> 24) & 127;
        int pos = atomicAdd(&cnt2[dl], 1);
        csr[beg + (pre[dl] - hist[dl]) + pos] = (int)(p & 0xFFFFFFu);
    }
}

// ---------------- weight split: W[k][n] fp32 -> Wh/Wl[n][k] bf16 (RNE) ----------------
__global__ void wsplit_kernel(const float* __restrict__ Wsrc, short* __restrict__ Whi,
                              short* __restrict__ Wlo) {
    int i = blockIdx.x * 256 + threadIdx.x;   // i = n*128 + k
    if (i >= 128 * 128) return;
    int n = i >> 7, k = i & 127;
    float v = Wsrc[k * 128 + n];
    unsigned int u = __float_as_uint(v);
    unsigned int hi = (u + 0x7FFFu + ((u >> 16) & 1)) & 0xFFFF0000u;
    float hf = __uint_as_float(hi);
    float lo = v - hf;
    unsigned int ul = __float_as_uint(lo);
    unsigned int lo16 = (ul + 0x7FFFu + ((ul >> 16) & 1)) >> 16;
    Whi[i] = (short)(hi >> 16);
    Wlo[i] = (short)lo16;
}

// ---------------- MFMA GEMM: C[N x 128] = affine(A)[N x 128] @ W[128 x 128] ----------------
template <bool OUT_F16>
__global__ __launch_bounds__(256) void gemm_mfma(const float* __restrict__ A,
                                                 const short* __restrict__ Wh,
                                                 const short* __restrict__ Wl,
                                                 const float* __restrict__ aff_s,
                                                 const float* __restrict__ aff_t,
                                                 const float* __restrict__ bias,
                                                 const float* __restrict__ rowscale,
                                                 void* __restrict__ outp, int N) {
    int w = threadIdx.x >> 6;
    int lane = threadIdx.x & 63;
    int l15 = lane & 15, lg = lane >> 4;
    int r0 = blockIdx.x * 128 + (w >> 1) * 64;
    int c0 = (w & 1) * 64;

    f32x4 acc[4][4];
    #pragma unroll
    for (int tc = 0; tc < 4; tc++) {
        float bz = bias ? bias[c0 + tc * 16 + l15] : 0.0f;
        #pragma unroll
        for (int tr = 0; tr < 4; tr++) {
            acc[tr][tc][0] = bz; acc[tr][tc][1] = bz;
            acc[tr][tc][2] = bz; acc[tr][tc][3] = bz;
        }
    }

    #pragma unroll
    for (int kt = 0; kt < 4; kt++) {
        int kk = kt * 32 + lg * 8;

        bf16x8 bh[4], bl[4];
        #pragma unroll
        for (int tc = 0; tc < 4; tc++) {
            int n = c0 + tc * 16 + l15;
            bh[tc] = *(const bf16x8*)(Wh + n * 128 + kk);
            bl[tc] = *(const bf16x8*)(Wl + n * 128 + kk);
        }

        float sv[8], tv[8];
        if (aff_s) {
            *(float4*)&sv[0] = *(const float4*)(aff_s + kk);
            *(float4*)&sv[4] = *(const float4*)(aff_s + kk + 4);
            *(float4*)&tv[0] = *(const float4*)(aff_t + kk);
            *(float4*)&tv[4] = *(const float4*)(aff_t + kk + 4);
        }

        bf16x8 ah[4], al[4];
        #pragma unroll
        for (int tr = 0; tr < 4; tr++) {
            int row = min(r0 + tr * 16 + l15, N - 1);
            const float* ap = A + (size_t)row * 128 + kk;
            float v[8];
            *(float4*)&v[0] = *(const float4*)ap;
            *(float4*)&v[4] = *(const float4*)(ap + 4);
            if (aff_s) {
                #pragma unroll
                for (int j = 0; j < 8; j++) v[j] = fmaf(v[j], sv[j], tv[j]);
            }
            split8(v, ah[tr], al[tr]);
        }

        #pragma unroll
        for (int tr = 0; tr < 4; tr++) {
            #pragma unroll
            for (int tc = 0; tc < 4; tc++) {
                acc[tr][tc] = __builtin_amdgcn_mfma_f32_16x16x32_bf16(ah[tr], bh[tc], acc[tr][tc], 0, 0, 0);
                acc[tr][tc] = __builtin_amdgcn_mfma_f32_16x16x32_bf16(ah[tr], bl[tc], acc[tr][tc], 0, 0, 0);
                acc[tr][tc] = __builtin_amdgcn_mfma_f32_16x16x32_bf16(al[tr], bh[tc], acc[tr][tc], 0, 0, 0);
            }
        }
    }

    #pragma unroll
    for (int tr = 0; tr < 4; tr++) {
        #pragma unroll
        for (int r = 0; r < 4; r++) {
            int row = r0 + tr * 16 + lg * 4 + r;
            if (row < N) {
                float sc = rowscale ? rowscale[row] : 1.0f;
                #pragma unroll
                for (int tc = 0; tc < 4; tc++) {
                    int col = c0 + tc * 16 + l15;
                    float val = acc[tr][tc][r] * sc;
                    if (OUT_F16) {
                        ((__half*)outp)[(size_t)row * 128 + col] = __float2half(val);
                    } else {
                        ((float*)outp)[(size_t)row * 128 + col] = val;
                    }
                }
            }
        }
    }
}

// ---------------- gather (fp16 in, fp32 out) ----------------
__global__ __launch_bounds__(256) void gather_kernel(const __half* __restrict__ hws,
                                                     const int* __restrict__ csr_src,
                                                     const int* __restrict__ offs,
                                                     const float* __restrict__ dinv,
                                                     const float* __restrict__ bias,
                                                     float* __restrict__ out,
                                                     int N, int relu) {
    int lane = threadIdx.x & 63;
    int node = blockIdx.x * 4 + (threadIdx.x >> 6);
    if (node >= N) return;
    int lo = offs[node], hi = offs[node + 1];

    float2 acc = make_float2(0.f, 0.f);
    int j = lo;
    for (; j + 3 < hi; j += 4) {
        int s0 = csr_src[j], s1 = csr_src[j + 1], s2 = csr_src[j + 2], s3 = csr_src[j + 3];
        float2 v0 = __half22float2(((const __half2*)(hws + (size_t)s0 * HDIM))[lane]);
        float2 v1 = __half22float2(((const __half2*)(hws + (size_t)s1 * HDIM))[lane]);
        float2 v2 = __half22float2(((const __half2*)(hws + (size_t)s2 * HDIM))[lane]);
        float2 v3 = __half22float2(((const __half2*)(hws + (size_t)s3 * HDIM))[lane]);
        acc.x += v0.x + v1.x + v2.x + v3.x;
        acc.y += v0.y + v1.y + v2.y + v3.y;
    }
    for (; j < hi; j++) {
        int s = csr_src[j];
        float2 v = __half22float2(((const __half2*)(hws + (size_t)s * HDIM))[lane]);
        acc.x += v.x; acc.y += v.y;
    }
    float2 vs = __half22float2(((const __half2*)(hws + (size_t)node * HDIM))[lane]);
    float di = dinv[node];
    float2 b = ((const float2*)bias)[lane];
    float ox = di * (acc.x + vs.x) + b.x;
    float oy = di * (acc.y + vs.y) + b.y;
    if (relu) { ox = fmaxf(ox, 0.f); oy = fmaxf(oy, 0.f); }
    ((float2*)(out + (size_t)node * HDIM))[lane] = make_float2(ox, oy);
}

// ---------------- batchnorm stats ----------------
__global__ __launch_bounds__(256) void bn_stats_kernel(const float* __restrict__ h,
                                                       float* __restrict__ stats, int N) {
    int f = threadIdx.x & 127;
    int half_ = threadIdx.x >> 7;
    float s = 0.f, s2 = 0.f;
    for (int n = blockIdx.x * 2 + half_; n < N; n += gridDim.x * 2) {
        float v = h[(size_t)n * HDIM + f];
        s += v;
        s2 += v * v;
    }
    __shared__ float ls[256], ls2[256];
    ls[threadIdx.x] = s;
    ls2[threadIdx.x] = s2;
    __syncthreads();
    if (half_ == 0) {
        s = ls[f] + ls[f + 128];
        s2 = ls2[f] + ls2[f + 128];
        atomicAdd(&stats[f], s);
        atomicAdd(&stats[128 + f], s2);
    }
}

__global__ void bn_finalize(const float* __restrict__ stats, const float* __restrict__ gamma,
                            const float* __restrict__ beta, float* __restrict__ aff_s,
                            float* __restrict__ aff_t, int N) {
    int f = threadIdx.x;  // 128
    float inv = 1.0f / (float)N;
    float m = stats[f] * inv;
    float var = stats[128 + f] * inv - m * m;
    float s = gamma[f] * rsqrtf(var + 1e-5f);
    aff_s[f] = s;
    aff_t[f] = beta[f] - m * s;
}

// ---------------- pool ----------------
__device__ __forceinline__ int lower_bound_i(const int* __restrict__ arr, int n, int val) {
    int lo = 0, hi = n;
    while (lo < hi) {
        int mid = (lo + hi) >> 1;
        if (arr[mid] < val) lo = mid + 1; else hi = mid;
    }
    return lo;
}

__global__ void pool_kernel(const float* __restrict__ h, const int* __restrict__ batch,
                            float* __restrict__ out, int N, int G) {
    int g = blockIdx.x;
    int lo = lower_bound_i(batch, N, g);
    int hi = lower_bound_i(batch, N, g + 1);
    int f = threadIdx.x;
    float s = 0.f;
    for (int n = lo; n < hi; n++) s += h[(size_t)n * HDIM + f];
    float cnt = (float)(hi - lo);
    out[(size_t)g * HDIM + f] = s / fmaxf(cnt, 1.0f);
}

// ---------------- launch ----------------
extern "C" void kernel_launch(void* const* d_in, const int* in_sizes, int n_in,
                              void* d_out, int out_size, void* d_ws, size_t ws_size,
                              hipStream_t stream) {
    const float* x      = (const float*)d_in[0];
    const int*   ei     = (const int*)d_in[1];
    const int*   batch  = (const int*)d_in[2];
    const float* W_emb  = (const float*)d_in[3];
    const float* b_emb  = (const float*)d_in[4];
    const float* W_conv = (const float*)d_in[5];
    const float* b_conv = (const float*)d_in[6];
    const float* gamma  = (const float*)d_in[7];
    const float* beta   = (const float*)d_in[8];

    const int E = in_sizes[1] / 2;
    const int N = in_sizes[2];
    const int G = out_size / HDIM;
    const int DEPTH = 4;

    const int* srcp = ei;
    const int* dstp = ei + E;
    float* out = (float*)d_out;

    size_t NH = (size_t)N * HDIM;
    size_t npad = ((size_t)N + 63) & ~(size_t)63;
    size_t epad = ((size_t)E + 63) & ~(size_t)63;
    int nb = (N + 127) / 128;  // buckets (<= NBMAX)

    float* ws = (float*)d_ws;
    float* dinv    = ws;                           // npad
    int*   offs    = (int*)(dinv + npad);          // npad + 64
    int*   bases   = offs + npad + 64;             // NBMAX+1 (pad 1024)
    int*   cursor  = bases + 1024;                 // NBMAX
    int*   bcount  = cursor + NBMAX;               // NBMAX
    int*   csr     = bcount + NBMAX;               // epad
    unsigned* ebuf = (unsigned*)(csr + epad);      // epad
    float* stats   = (float*)(ebuf + epad);        // 256
    float* aff_s   = stats + 256;                  // 128
    float* aff_t   = aff_s + 128;                  // 128
    short* wt      = (short*)(aff_t + 128);        // 5 * 2 * 16384 shorts
    float* hbuf    = (float*)(wt + 5 * 2 * 16384); // NH floats
    __half* hws16  = (__half*)(hbuf + NH);         // NH halves

    // ---- weight split (5 matrices: emb + 4 conv) ----
    wsplit_kernel<<<64, 256, 0, stream>>>(W_emb, wt, wt + 16384);
    for (int l = 0; l < DEPTH; l++) {
        short* whi = wt + (size_t)(l + 1) * 32768;
        wsplit_kernel<<<64, 256, 0, stream>>>(W_conv + (size_t)l * 16384, whi, whi + 16384);
    }

    // ---- CSR build (two-level binning) ----
    hipMemsetAsync(bcount, 0, NBMAX * sizeof(int), stream);
    bucket_hist<<<256, 256, 0, stream>>>(dstp, bcount, E);
    bucket_scan<<<1, 256, 0, stream>>>(bcount, bases, cursor, E);
    bucket_scatter<<<(E + CHUNK - 1) / CHUNK, 256, 0, stream>>>(srcp, dstp, cursor, ebuf, E);
    bucket_finalize<<<nb, 256, 0, stream>>>(ebuf, bases, csr, offs, dinv, N, E);

    int gemm_blocks = (N + 127) / 128;

    // ---- embedding: hbuf = x @ W_emb + b_emb (fp32 out) ----
    gemm_mfma<false><<<gemm_blocks, 256, 0, stream>>>(x, wt, wt + 16384, nullptr, nullptr,
                                                      b_emb, nullptr, hbuf, N);

    int gather_blocks = (N + 3) / 4;

    for (int l = 0; l < DEPTH; l++) {
        short* whi = wt + (size_t)(l + 1) * 32768;
        gemm_mfma<true><<<gemm_blocks, 256, 0, stream>>>(hbuf, whi, whi + 16384,
                                                         (l > 0) ? aff_s : nullptr,
                                                         (l > 0) ? aff_t : nullptr,
                                                         nullptr, dinv, hws16, N);
        gather_kernel<<<gather_blocks, 256, 0, stream>>>(hws16, csr, offs, dinv,
                                                         b_conv + (size_t)l * HDIM, hbuf,
                                                         N, (l < DEPTH - 1) ? 1 : 0);
        if (l < DEPTH - 1) {
            hipMemsetAsync(stats, 0, 256 * sizeof(float), stream);
            bn_stats_kernel<<<512, 256, 0, stream>>>(hbuf, stats, N);
            bn_finalize<<<1, 128, 0, stream>>>(stats, gamma + (size_t)l * HDIM,
                                               beta + (size_t)l * HDIM, aff_s, aff_t, N);
        }
    }

    pool_kernel<<<G, HDIM, 0, stream>>>(hbuf, batch, out, N, G);
}